// Round 2
// baseline (96.534 us; speedup 1.0000x reference)
//
#include <hip/hip_runtime.h>
#include <cstdint>

// ---------------------------------------------------------------------------
// TileTask_62277025792545: bit-serial int8 conv emulation.
//   conv: 8 bit-planes of cast_in (two's complement), each 3x3x64->64 conv,
//   per-plane q = 2*clip(rne(y/2),-128,127), recombine with [1,2,..,64,-128],
//   +bias, +merge, quant(cmult), +gather, quant(0.75), relu, quant(1), pool2x2.
// Implementation: implicit-GEMM MFMA (i8), M=(pixel,plane), N=cout, K=ci*9=576.
// Wave tile: 32 rows = 2x2 pool-quad (4 px) x 8 planes  X  32 cout.
// A-fragments are built on the fly: (bytes >> plane) & 0x01010101 IS the i8
// fragment (values 0/1), no bf16 expansion needed. i32 accum is exact.
// ---------------------------------------------------------------------------

typedef int    i32x4  __attribute__((ext_vector_type(4)));
typedef int    i32x16 __attribute__((ext_vector_type(16)));

#define XB_OFF   0u
#define XB_BYTES 4326400u                      // 4*130*130*64 u8, padded NHWC
#define MG_OFF   (XB_OFF + XB_BYTES)           // merge int8 NHWC
#define MG_BYTES 4194304u                      // 4*128*128*64
#define GT_OFF   (MG_OFF + MG_BYTES)           // gather int8 NHWC
#define WPK_OFF  (GT_OFF + MG_BYTES)           // packed i8 B-frags
#define WPK_BYTES 36864u                       // 18*2*64*16 i8
#define OUTN_OFF (WPK_OFF + WPK_BYTES)         // f32 NHWC pooled out

// NCHW f32 (ints in [-128,127]) -> NHWC bytes (two's complement), 3 tensors in
// one launch. which==0 (cast_in) adds the conv halo (dst 130x130, border
// pre-zeroed by memset).
__global__ __launch_bounds__(256) void k_stage(const float* __restrict__ s_cast,
                                               const float* __restrict__ s_mg,
                                               const float* __restrict__ s_gt,
                                               uint8_t* __restrict__ ws) {
  const int blk = blockIdx.x;
  const int which = blk >> 9, rem = blk & 511;
  const float* src = which == 0 ? s_cast : (which == 1 ? s_mg : s_gt);
  uint8_t* dst = which == 0 ? (ws + XB_OFF)
                            : (which == 1 ? (ws + MG_OFF) : (ws + GT_OFF));
  const int b = rem >> 7, h = rem & 127, t = threadIdx.x;
  __shared__ uint8_t lds[128 * 68];            // [w][ci], +4 pad for banks
  const float* s0 = src + ((size_t)(b * 64) * 128 + h) * 128;
#pragma unroll
  for (int ci0 = 0; ci0 < 64; ci0 += 2) {
    const int ci = ci0 + (t >> 7), w = t & 127;
    const float v = s0[ci * 16384 + w];        // coalesced over w
    lds[w * 68 + ci] = (uint8_t)((int)v & 0xFF);
  }
  __syncthreads();
  uint8_t* d0 = dst + (which == 0 ? (((size_t)b * 130 + h + 1) * 130 + 1) * 64
                                  : ((size_t)(b * 128 + h) * 128) * 64);
#pragma unroll
  for (int j = 0; j < 8; ++j) {                // 8192B contiguous per (b,h)
    const int f = j * 256 + t;
    const int w = f >> 4, ci4 = f & 15;
    const uint32_t val = *(const uint32_t*)&lds[w * 68 + ci4 * 4];
    *(uint32_t*)(d0 + (size_t)f * 4) = val;
  }
}

// Weight pack: W[co][ci][kh][kw] f32 -> wpk[c][g][lane][16] i8 in the
// v_mfma_i32_32x32x32_i8 B-fragment layout: col=lane&31, k=c*32+(lane>>5)*16+i
// (natural slot order; any HW-internal slot permutation cancels because the
// A-build uses the same natural order).
__global__ __launch_bounds__(256) void k_pack_w(const float* __restrict__ wsrc,
                                                int8_t* __restrict__ wpk) {
  const int idx = blockIdx.x * 256 + threadIdx.x;   // grid covers exactly 36864
  const int i = idx & 15, l = (idx >> 4) & 63, gg = (idx >> 10) & 1,
            c = idx >> 11;                          // c in [0,18)
  const int k = c * 32 + (l >> 5) * 16 + i;         // k = tap*64 + ci
  const int tap = k >> 6, ci = k & 63;
  const int kh = tap / 3, kw = tap % 3;
  const int cco = gg * 32 + (l & 31);
  const float wv = wsrc[((cco * 64 + ci) * 3 + kh) * 3 + kw];
  wpk[idx] = (int8_t)(int)wv;
}

__global__ __launch_bounds__(256) void k_main(
    const unsigned char* __restrict__ xb, const signed char* __restrict__ mg,
    const signed char* __restrict__ gt, const int8_t* __restrict__ wpk,
    const float* __restrict__ bias, const float* __restrict__ cti,
    const float* __restrict__ cts, const float* __restrict__ sti,
    const float* __restrict__ sts, const float* __restrict__ ati,
    const float* __restrict__ ats, float* __restrict__ outn) {
  const int lane = threadIdx.x & 63;
  const int wvid = blockIdx.x * 4 + (threadIdx.x >> 6);
  const int g = wvid & 1;                       // cout half
  const int t2 = wvid >> 1;
  const int wog = t2 & 7;                       // 8 pooled cols per wave
  const int ho = (t2 >> 3) & 63;
  const int b = t2 >> 9;

  // B-fragments held in registers across all 8 quads (/8 on L2 B-traffic)
  i32x4 Bf[18];
#pragma unroll
  for (int c = 0; c < 18; ++c)
    Bf[c] = *(const i32x4*)(wpk + ((size_t)(c * 2 + g) * 64 + lane) * 16);

  const int pix = (lane & 31) >> 3;             // A row = pix*8 + plane
  const int plane = lane & 7;
  const int khalf = lane >> 5;
  const int dh = pix >> 1, dw = pix & 1;
  const int h = ho * 2;
  // one row pointer per kh; per-chunk offset = kw*64 + (c&1)*32 fits the
  // 13-bit global_load immediate -> zero addressing VALU in the hot loop
  const unsigned char* xr0 =
      xb + ((size_t)((b * 130 + h + dh) * 130) + dw) * 64 + khalf * 16;
  const unsigned char* xr1 = xr0 + 130 * 64;
  const unsigned char* xr2 = xr1 + 130 * 64;

  const int co = g * 32 + (lane & 31);
  const float bs = bias[co];
  const float cm = ldexpf(cti[co], (int)cts[co]);   // i * 2^s == i / 2^-s exact
  const float sm = ldexpf(sti[0], (int)sts[0]);
  const float am = ldexpf(ati[0], (int)ats[0]);
  float pwl[4];                                 // this lane's 4 plane weights
  pwl[0] = khalf ? 16.f : 1.f;
  pwl[1] = khalf ? 32.f : 2.f;
  pwl[2] = khalf ? 64.f : 4.f;
  pwl[3] = khalf ? -128.f : 8.f;

  for (int q = 0; q < 8; ++q) {
    const int wo = wog * 8 + q;
    const int w = wo * 2;
    const unsigned char* r0 = xr0 + w * 64;
    const unsigned char* r1 = xr1 + w * 64;
    const unsigned char* r2 = xr2 + w * 64;
    i32x16 acc = {};
#pragma unroll
    for (int c = 0; c < 18; ++c) {              // K = 18 chunks of 32
      const int tap = c >> 1;
      const int kh = tap / 3, kw = tap % 3;     // compile-time after unroll
      const unsigned char* p =
          (kh == 0 ? r0 : (kh == 1 ? r1 : r2)) + kw * 64 + (c & 1) * 32;
      const uint4 vv = *(const uint4*)p;        // 16 ci bytes, L1-resident
      i32x4 av;
      av[0] = (int)((vv.x >> plane) & 0x01010101u);
      av[1] = (int)((vv.y >> plane) & 0x01010101u);
      av[2] = (int)((vv.z >> plane) & 0x01010101u);
      av[3] = (int)((vv.w >> plane) & 0x01010101u);
      acc = __builtin_amdgcn_mfma_i32_32x32x32_i8(av, Bf[c], acc, 0, 0, 0);
    }
    // ---- epilogue: reg r -> pixel=r>>2, plane=(r&3)+4*khalf ----
    float psum[4];
#pragma unroll
    for (int px = 0; px < 4; ++px) {
      float s = 0.f;
#pragma unroll
      for (int j = 0; j < 4; ++j) {
        const float y = (float)acc[px * 4 + j];
        const float qq = fminf(fmaxf(rintf(y * 0.5f), -128.f), 127.f);
        s = fmaf(pwl[j], 2.f * qq, s);          // plane_w * 2*clip(rne(y/2))
      }
      psum[px] = s;
    }
#pragma unroll
    for (int px = 0; px < 4; ++px)              // combine plane halves
      psum[px] += __shfl_xor(psum[px], 32);

    float po = -3.0e38f;
#pragma unroll
    for (int px = 0; px < 4; ++px) {
      const int hh = h + (px >> 1), ww = w + (px & 1);
      const size_t moff = ((size_t)((b * 128 + hh) * 128 + ww)) * 64 + co;
      const float x1 = psum[px] + bs + (float)mg[moff];
      const float x2 = fminf(fmaxf(rintf(x1 * cm), -128.f), 127.f);
      const float x3 = x2 + (float)gt[moff];
      const float x4 = fminf(fmaxf(rintf(x3 * sm), -128.f), 127.f);
      const float x5 = fmaxf(x4, 0.f);
      const float x6 = fminf(fmaxf(rintf(x5 * am), -128.f), 127.f);
      po = fmaxf(po, x6);                       // 2x2 maxpool, in-lane
    }
    if (lane < 32)
      outn[((size_t)((b * 64 + ho) * 64 + wo)) * 64 + co] = po;
  }
}

// pooled NHWC f32 -> NCHW f32 output (coalesced both sides via LDS tile)
__global__ __launch_bounds__(256) void k_tr_out(const float* __restrict__ outn,
                                                float* __restrict__ outp) {
  const int blk = blockIdx.x, b = blk >> 6, ho = blk & 63, t = threadIdx.x;
  __shared__ float lds[64 * 65];
  const float* s0 = outn + (size_t)(b * 64 + ho) * 4096;
#pragma unroll
  for (int j = 0; j < 16; ++j) {
    const int f = j * 256 + t, wo = f >> 6, co = f & 63;
    lds[wo * 65 + co] = s0[f];
  }
  __syncthreads();
#pragma unroll
  for (int j = 0; j < 16; ++j) {
    const int f = j * 256 + t, co = f >> 6, wo = f & 63;
    outp[(((size_t)(b * 64 + co)) * 64 + ho) * 64 + wo] = lds[wo * 65 + co];
  }
}

extern "C" void kernel_launch(void* const* d_in, const int* in_sizes, int n_in,
                              void* d_out, int out_size, void* d_ws, size_t ws_size,
                              hipStream_t stream) {
  const float* cast_in = (const float*)d_in[0];
  const float* merge_in = (const float*)d_in[1];
  const float* gather_in = (const float*)d_in[2];
  const float* conv_w = (const float*)d_in[3];
  const float* conv_b = (const float*)d_in[4];
  const float* cti = (const float*)d_in[5];
  const float* cts = (const float*)d_in[6];
  const float* sti = (const float*)d_in[7];
  const float* sts = (const float*)d_in[8];
  const float* ati = (const float*)d_in[9];
  const float* ats = (const float*)d_in[10];

  uint8_t* ws = (uint8_t*)d_ws;
  uint8_t* xb = ws + XB_OFF;
  int8_t* mg = (int8_t*)(ws + MG_OFF);
  int8_t* gt = (int8_t*)(ws + GT_OFF);
  int8_t* wpk = (int8_t*)(ws + WPK_OFF);
  float* outn = (float*)(ws + OUTN_OFF);

  hipMemsetAsync(xb, 0, XB_BYTES, stream);      // zero conv halo border
  k_stage<<<1536, 256, 0, stream>>>(cast_in, merge_in, gather_in, ws);
  k_pack_w<<<144, 256, 0, stream>>>(conv_w, wpk);
  k_main<<<1024, 256, 0, stream>>>(xb, mg, gt, wpk, conv_b, cti, cts, sti, sts,
                                   ati, ats, outn);
  k_tr_out<<<256, 256, 0, stream>>>(outn, (float*)d_out);
}

// Round 3
// 49.414 us; speedup vs baseline: 1.9536x; 1.9536x over previous
//
#include <hip/hip_runtime.h>
#include <cstdint>

// ---------------------------------------------------------------------------
// TileTask_62277025792545: bit-serial int8 conv emulation.
//   conv: 8 bit-planes of cast_in (two's complement), each 3x3x64->64 conv,
//   per-plane q = 2*clip(rne(y/2),-128,127), recombine with [1,2,..,64,-128],
//   +bias, +merge, quant(cmult), +gather, quant(0.75), relu, quant(1), pool2x2.
// Implementation: implicit-GEMM MFMA (i8), M=(pixel,plane), N=cout, K=ci*9=576.
// Wave tile: 32 rows = 2x2 pool-quad (4 px) x 8 planes  X  32 cout.
// R3: x-strip staged in LDS per block (kills the R2 L2-latency serial chain);
// mg/gt epilogue loads hoisted above the MFMA chain; pack fused into stage.
// ---------------------------------------------------------------------------

typedef int i32x4  __attribute__((ext_vector_type(4)));
typedef int i32x16 __attribute__((ext_vector_type(16)));

#define XB_OFF   0u
#define XB_BYTES 4326400u                      // 4*130*130*64 u8, padded NHWC
#define MG_OFF   (XB_OFF + XB_BYTES)           // merge int8 NHWC
#define MG_BYTES 4194304u                      // 4*128*128*64
#define GT_OFF   (MG_OFF + MG_BYTES)           // gather int8 NHWC
#define WPK_OFF  (GT_OFF + MG_BYTES)           // packed i8 B-frags
#define WPK_BYTES 36864u                       // 18*2*64*16 i8
#define OUTN_OFF (WPK_OFF + WPK_BYTES)         // f32 NHWC pooled out

// NCHW f32 (ints in [-128,127]) -> NHWC bytes, 3 tensors + weight pack in one
// launch. which==0 (cast_in) adds the conv halo (130x130, border pre-zeroed).
// Blocks >= 1536: pack W[co][ci][kh][kw] -> wpk[c][g][lane][16] i8 in the
// v_mfma_i32_32x32x32_i8 B-frag layout: col=lane&31, k=c*32+(lane>>5)*16+i.
__global__ __launch_bounds__(256) void k_stage(const float* __restrict__ s_cast,
                                               const float* __restrict__ s_mg,
                                               const float* __restrict__ s_gt,
                                               const float* __restrict__ wsrc,
                                               uint8_t* __restrict__ ws) {
  const int blk = blockIdx.x, t = threadIdx.x;
  if (blk >= 1536) {                           // ---- weight pack path ----
    const int idx = (blk - 1536) * 256 + t;    // covers exactly 36864
    const int i = idx & 15, l = (idx >> 4) & 63, gg = (idx >> 10) & 1,
              c = idx >> 11;                   // c in [0,18)
    const int k = c * 32 + (l >> 5) * 16 + i;  // k = tap*64 + ci
    const int tap = k >> 6, ci = k & 63;
    const int kh = tap / 3, kw = tap % 3;
    const int cco = gg * 32 + (l & 31);
    const float wv = wsrc[((cco * 64 + ci) * 3 + kh) * 3 + kw];
    ((int8_t*)(ws + WPK_OFF))[idx] = (int8_t)(int)wv;
    return;
  }
  const int which = blk >> 9, rem = blk & 511;
  const float* src = which == 0 ? s_cast : (which == 1 ? s_mg : s_gt);
  uint8_t* dst = which == 0 ? (ws + XB_OFF)
                            : (which == 1 ? (ws + MG_OFF) : (ws + GT_OFF));
  const int b = rem >> 7, h = rem & 127;
  __shared__ uint8_t lds[128 * 68];            // [w][ci], +4 pad for banks
  const float* s0 = src + ((size_t)(b * 64) * 128 + h) * 128;
#pragma unroll
  for (int ci0 = 0; ci0 < 64; ci0 += 2) {
    const int ci = ci0 + (t >> 7), w = t & 127;
    const float v = s0[ci * 16384 + w];        // coalesced over w
    lds[w * 68 + ci] = (uint8_t)((int)v & 0xFF);
  }
  __syncthreads();
  uint8_t* d0 = dst + (which == 0 ? (((size_t)b * 130 + h + 1) * 130 + 1) * 64
                                  : ((size_t)(b * 128 + h) * 128) * 64);
#pragma unroll
  for (int j = 0; j < 8; ++j) {                // 8192B contiguous per (b,h)
    const int f = j * 256 + t;
    const int w = f >> 4, ci4 = f & 15;
    const uint32_t val = *(const uint32_t*)&lds[w * 68 + ci4 * 4];
    *(uint32_t*)(d0 + (size_t)f * 4) = val;
  }
}

__global__ __launch_bounds__(256, 4) void k_main(
    const unsigned char* __restrict__ xb, const signed char* __restrict__ mg,
    const signed char* __restrict__ gt, const int8_t* __restrict__ wpk,
    const float* __restrict__ bias, const float* __restrict__ cti,
    const float* __restrict__ cts, const float* __restrict__ sti,
    const float* __restrict__ sts, const float* __restrict__ ati,
    const float* __restrict__ ats, float* __restrict__ outn) {
  const int tid = threadIdx.x, lane = tid & 63, wvid = tid >> 6;
  const int g = wvid & 1;                      // cout half
  const int wog = wvid >> 1;                   // {0,1}: 8 pooled cols each
  const int blk = blockIdx.x;
  const int wq = blk & 3, ho = (blk >> 2) & 63, b = blk >> 8;
  const int h = ho * 2, w0 = wq * 32;          // block covers cols w0..w0+33

  __shared__ uint4 ldsx4[640];                 // x strip: [4 rows][40 cols][64 ci]
  uint8_t* ldsx = (uint8_t*)ldsx4;

  // ---- stage x rows h..h+3, padded cols w0..w0+33 into LDS ----
  {
    const unsigned char* xrow = xb + ((size_t)(b * 130 + h) * 130 + w0) * 64;
#pragma unroll
    for (int i = 0; i < 3; ++i) {
      const int s = i * 256 + tid;             // 640 x 16B segments
      if (s < 640) {
        const int row = s / 160, rm = s - row * 160;
        const int col = rm >> 2, ci16 = rm & 3;
        const int gcol = col < 34 ? col : 33;  // pad cols: safe duplicate
        const uint4 v =
            *(const uint4*)(xrow + ((size_t)row * 130 + gcol) * 64 + ci16 * 16);
        *(uint4*)(ldsx + (row * 40 + col) * 64 + ci16 * 16) = v;
      }
    }
  }

  // ---- B fragments in registers (72 VGPR), reused by all 8 quads ----
  i32x4 Bf[18];
#pragma unroll
  for (int c = 0; c < 18; ++c)
    Bf[c] = *(const i32x4*)(wpk + ((size_t)(c * 2 + g) * 64 + lane) * 16);

  const int pix = (lane & 31) >> 3;            // A row = pix*8 + plane
  const int plane = lane & 7;
  const int khalf = lane >> 5;
  const int dh = pix >> 1, dw = pix & 1;
  const uint8_t* lbase0 = ldsx + (dh * 40 + dw) * 64 + khalf * 16;

  const int co = g * 32 + (lane & 31);
  const float bs = bias[co];
  const float cm = ldexpf(cti[co], (int)cts[co]);  // i * 2^s == i / 2^-s exact
  const float sm = ldexpf(sti[0], (int)sts[0]);
  const float am = ldexpf(ati[0], (int)ats[0]);
  float pwl[4];                                // this lane's 4 plane weights
  pwl[0] = khalf ? 16.f : 1.f;
  pwl[1] = khalf ? 32.f : 2.f;
  pwl[2] = khalf ? 64.f : 4.f;
  pwl[3] = khalf ? -128.f : 8.f;

  __syncthreads();                             // x strip ready; no more barriers

  for (int q = 0; q < 8; ++q) {
    const int wol = wog * 8 + q;               // 0..15 within block
    const int wo = wq * 16 + wol;
    const int w = wo * 2;
    const uint8_t* lb = lbase0 + wol * 128;

    // hoist epilogue byte-loads above the MFMA chain (latency hides under it)
    int mgv[4], gtv[4];
#pragma unroll
    for (int px = 0; px < 4; ++px) {
      const size_t moff =
          ((size_t)((b * 128 + h + (px >> 1)) * 128 + w + (px & 1))) * 64 + co;
      mgv[px] = mg[moff];
      gtv[px] = gt[moff];
    }

    i32x16 acc = {};
#pragma unroll
    for (int c = 0; c < 18; ++c) {             // K = 18 chunks of 32
      const int tap = c >> 1;
      const int kh = tap / 3, kw = tap % 3;    // compile-time after unroll
      const uint4 vv =                         // imm-offset ds_read_b128
          *(const uint4*)(lb + kh * 2560 + kw * 64 + (c & 1) * 32);
      i32x4 av;                                // bit-plane extract IS the frag
      av[0] = (int)((vv.x >> plane) & 0x01010101u);
      av[1] = (int)((vv.y >> plane) & 0x01010101u);
      av[2] = (int)((vv.z >> plane) & 0x01010101u);
      av[3] = (int)((vv.w >> plane) & 0x01010101u);
      acc = __builtin_amdgcn_mfma_i32_32x32x32_i8(av, Bf[c], acc, 0, 0, 0);
    }

    // ---- epilogue: reg r -> pixel=r>>2, plane=(r&3)+4*khalf ----
    float psum[4];
#pragma unroll
    for (int px = 0; px < 4; ++px) {
      float s = 0.f;
#pragma unroll
      for (int j = 0; j < 4; ++j) {
        const float y = (float)acc[px * 4 + j];
        const float qq = fminf(fmaxf(rintf(y * 0.5f), -128.f), 127.f);
        s = fmaf(pwl[j], 2.f * qq, s);         // plane_w * 2*clip(rne(y/2))
      }
      psum[px] = s;
    }
#pragma unroll
    for (int px = 0; px < 4; ++px)             // combine plane halves
      psum[px] += __shfl_xor(psum[px], 32);

    float po = -3.0e38f;
#pragma unroll
    for (int px = 0; px < 4; ++px) {
      const float x1 = psum[px] + bs + (float)mgv[px];
      const float x2 = fminf(fmaxf(rintf(x1 * cm), -128.f), 127.f);
      const float x3 = x2 + (float)gtv[px];
      const float x4 = fminf(fmaxf(rintf(x3 * sm), -128.f), 127.f);
      const float x5 = fmaxf(x4, 0.f);
      const float x6 = fminf(fmaxf(rintf(x5 * am), -128.f), 127.f);
      po = fmaxf(po, x6);                      // 2x2 maxpool, in-lane
    }
    if (lane < 32)
      outn[((size_t)((b * 64 + ho) * 64 + wo)) * 64 + co] = po;
  }
}

// pooled NHWC f32 -> NCHW f32 output (coalesced both sides via LDS tile)
__global__ __launch_bounds__(256) void k_tr_out(const float* __restrict__ outn,
                                                float* __restrict__ outp) {
  const int blk = blockIdx.x, b = blk >> 6, ho = blk & 63, t = threadIdx.x;
  __shared__ float lds[64 * 65];
  const float* s0 = outn + (size_t)(b * 64 + ho) * 4096;
#pragma unroll
  for (int j = 0; j < 16; ++j) {
    const int f = j * 256 + t, wo = f >> 6, co = f & 63;
    lds[wo * 65 + co] = s0[f];
  }
  __syncthreads();
#pragma unroll
  for (int j = 0; j < 16; ++j) {
    const int f = j * 256 + t, co = f >> 6, wo = f & 63;
    outp[(((size_t)(b * 64 + co)) * 64 + ho) * 64 + wo] = lds[wo * 65 + co];
  }
}

extern "C" void kernel_launch(void* const* d_in, const int* in_sizes, int n_in,
                              void* d_out, int out_size, void* d_ws, size_t ws_size,
                              hipStream_t stream) {
  const float* cast_in = (const float*)d_in[0];
  const float* merge_in = (const float*)d_in[1];
  const float* gather_in = (const float*)d_in[2];
  const float* conv_w = (const float*)d_in[3];
  const float* conv_b = (const float*)d_in[4];
  const float* cti = (const float*)d_in[5];
  const float* cts = (const float*)d_in[6];
  const float* sti = (const float*)d_in[7];
  const float* sts = (const float*)d_in[8];
  const float* ati = (const float*)d_in[9];
  const float* ats = (const float*)d_in[10];

  uint8_t* ws = (uint8_t*)d_ws;
  uint8_t* xb = ws + XB_OFF;
  int8_t* mg = (int8_t*)(ws + MG_OFF);
  int8_t* gt = (int8_t*)(ws + GT_OFF);
  int8_t* wpk = (int8_t*)(ws + WPK_OFF);
  float* outn = (float*)(ws + OUTN_OFF);

  hipMemsetAsync(xb, 0, XB_BYTES, stream);     // zero conv halo border
  k_stage<<<1680, 256, 0, stream>>>(cast_in, merge_in, gather_in, conv_w, ws);
  k_main<<<1024, 256, 0, stream>>>(xb, mg, gt, wpk, conv_b, cti, cts, sti, sts,
                                   ati, ats, outn);
  k_tr_out<<<256, 256, 0, stream>>>(outn, (float*)d_out);
}

// Round 4
// 41.319 us; speedup vs baseline: 2.3363x; 1.1959x over previous
//
#include <hip/hip_runtime.h>
#include <cstdint>

// ---------------------------------------------------------------------------
// TileTask_62277025792545: bit-serial int8 conv emulation.
//   conv: 8 bit-planes of cast_in (two's complement), each 3x3x64->64 conv,
//   per-plane q = 2*clip(rne(y/2),-128,127), recombine with [1,2,..,64,-128],
//   +bias, +merge, quant(cmult), +gather, quant(0.75), relu, quant(1), pool2x2.
// Implementation: implicit-GEMM MFMA (i8), M=(pixel,plane), N=cout, K=ci*9=576.
// Wave tile: 32 rows = 2x2 pool-quad (4 px) x 8 planes  X  32 cout.
// R4: no memset (halo zeroed inside k_stage — the 4.3MB fill was a 40us
// rocclr kernel!); output transpose fused into k_main via a 4KB LDS tile.
// ---------------------------------------------------------------------------

typedef int i32x4  __attribute__((ext_vector_type(4)));
typedef int i32x16 __attribute__((ext_vector_type(16)));

#define XB_OFF   0u
#define XB_BYTES 4326400u                      // 4*130*130*64 u8, padded NHWC
#define MG_OFF   (XB_OFF + XB_BYTES)           // merge int8 NHWC
#define MG_BYTES 4194304u                      // 4*128*128*64
#define GT_OFF   (MG_OFF + MG_BYTES)           // gather int8 NHWC
#define WPK_OFF  (GT_OFF + MG_BYTES)           // packed i8 B-frags
#define WPK_BYTES 36864u                       // 18*2*64*16 i8

// NCHW f32 (ints in [-128,127]) -> NHWC bytes, 3 tensors + weight pack + halo
// zeroing, one launch. which==0 (cast_in) adds the conv halo offset (130x130).
// Blocks 1536..1679: pack W[co][ci][kh][kw] -> wpk[c][g][lane][16] i8 in the
// v_mfma_i32_32x32x32_i8 B-frag layout: col=lane&31, k=c*32+(lane>>5)*16+i.
// Blocks 1680..1687: zero xb halo rows 0 and 129 per batch. Side halo columns
// are zeroed by the cast-path blocks (their own row). No memset needed.
__global__ __launch_bounds__(256) void k_stage(const float* __restrict__ s_cast,
                                               const float* __restrict__ s_mg,
                                               const float* __restrict__ s_gt,
                                               const float* __restrict__ wsrc,
                                               uint8_t* __restrict__ ws) {
  const int blk = blockIdx.x, t = threadIdx.x;
  if (blk >= 1680) {                           // ---- halo top/bottom rows ----
    const int hb = blk - 1680;                 // 8 blocks: 4 b x {0,129}
    const int b = hb >> 1, r = (hb & 1) ? 129 : 0;
    uint8_t* base = ws + XB_OFF + ((size_t)(b * 130 + r) * 130) * 64;
    const uint4 z = {0, 0, 0, 0};
#pragma unroll
    for (int i = 0; i < 3; ++i) {
      const int s = i * 256 + t;
      if (s < 520) *(uint4*)(base + (size_t)s * 16) = z;   // 520*16 = 8320
    }
    return;
  }
  if (blk >= 1536) {                           // ---- weight pack path ----
    const int idx = (blk - 1536) * 256 + t;    // covers exactly 36864
    const int i = idx & 15, l = (idx >> 4) & 63, gg = (idx >> 10) & 1,
              c = idx >> 11;                   // c in [0,18)
    const int k = c * 32 + (l >> 5) * 16 + i;  // k = tap*64 + ci
    const int tap = k >> 6, ci = k & 63;
    const int kh = tap / 3, kw = tap % 3;
    const int cco = gg * 32 + (l & 31);
    const float wv = wsrc[((cco * 64 + ci) * 3 + kh) * 3 + kw];
    ((int8_t*)(ws + WPK_OFF))[idx] = (int8_t)(int)wv;
    return;
  }
  const int which = blk >> 9, rem = blk & 511;
  const float* src = which == 0 ? s_cast : (which == 1 ? s_mg : s_gt);
  uint8_t* dst = which == 0 ? (ws + XB_OFF)
                            : (which == 1 ? (ws + MG_OFF) : (ws + GT_OFF));
  const int b = rem >> 7, h = rem & 127;
  __shared__ uint8_t lds[128 * 68];            // [w][ci], +4 pad for banks
  const float* s0 = src + ((size_t)(b * 64) * 128 + h) * 128;
#pragma unroll
  for (int ci0 = 0; ci0 < 64; ci0 += 2) {
    const int ci = ci0 + (t >> 7), w = t & 127;
    const float v = s0[ci * 16384 + w];        // coalesced over w
    lds[w * 68 + ci] = (uint8_t)((int)v & 0xFF);
  }
  __syncthreads();
  if (which == 0) {
    uint8_t* row = dst + (((size_t)b * 130 + h + 1) * 130) * 64;
#pragma unroll
    for (int j = 0; j < 8; ++j) {              // interior cols 1..128
      const int f = j * 256 + t;
      const int w = f >> 4, ci4 = f & 15;
      const uint32_t val = *(const uint32_t*)&lds[w * 68 + ci4 * 4];
      *(uint32_t*)(row + 64 + (size_t)f * 4) = val;
    }
    if (t < 8) {                               // side halo cols 0 and 129
      const int col = (t < 4) ? 0 : 129, seg = t & 3;
      const uint4 z = {0, 0, 0, 0};
      *(uint4*)(row + (size_t)col * 64 + seg * 16) = z;
    }
  } else {
    uint8_t* d0 = dst + ((size_t)(b * 128 + h) * 128) * 64;
#pragma unroll
    for (int j = 0; j < 8; ++j) {              // 8192B contiguous per (b,h)
      const int f = j * 256 + t;
      const int w = f >> 4, ci4 = f & 15;
      const uint32_t val = *(const uint32_t*)&lds[w * 68 + ci4 * 4];
      *(uint32_t*)(d0 + (size_t)f * 4) = val;
    }
  }
}

__global__ __launch_bounds__(256, 4) void k_main(
    const unsigned char* __restrict__ xb, const signed char* __restrict__ mg,
    const signed char* __restrict__ gt, const int8_t* __restrict__ wpk,
    const float* __restrict__ bias, const float* __restrict__ cti,
    const float* __restrict__ cts, const float* __restrict__ sti,
    const float* __restrict__ sts, const float* __restrict__ ati,
    const float* __restrict__ ats, float* __restrict__ outp) {
  const int tid = threadIdx.x, lane = tid & 63, wvid = tid >> 6;
  const int g = wvid & 1;                      // cout half
  const int wog = wvid >> 1;                   // {0,1}: 8 pooled cols each
  const int blk = blockIdx.x;
  const int wq = blk & 3, ho = (blk >> 2) & 63, b = blk >> 8;
  const int h = ho * 2, w0 = wq * 32;          // block covers cols w0..w0+33

  __shared__ uint4 ldsx4[640];                 // x strip: [4 rows][40 cols][64 ci]
  __shared__ float po_lds[16 * 64];            // pooled out: [wo_local][co]
  uint8_t* ldsx = (uint8_t*)ldsx4;

  // ---- stage x rows h..h+3, padded cols w0..w0+33 into LDS ----
  {
    const unsigned char* xrow = xb + ((size_t)(b * 130 + h) * 130 + w0) * 64;
#pragma unroll
    for (int i = 0; i < 3; ++i) {
      const int s = i * 256 + tid;             // 640 x 16B segments
      if (s < 640) {
        const int row = s / 160, rm = s - row * 160;
        const int col = rm >> 2, ci16 = rm & 3;
        const int gcol = col < 34 ? col : 33;  // pad cols: safe duplicate
        const uint4 v =
            *(const uint4*)(xrow + ((size_t)row * 130 + gcol) * 64 + ci16 * 16);
        *(uint4*)(ldsx + (row * 40 + col) * 64 + ci16 * 16) = v;
      }
    }
  }

  // ---- B fragments in registers (72 VGPR), reused by all 8 quads ----
  i32x4 Bf[18];
#pragma unroll
  for (int c = 0; c < 18; ++c)
    Bf[c] = *(const i32x4*)(wpk + ((size_t)(c * 2 + g) * 64 + lane) * 16);

  const int pix = (lane & 31) >> 3;            // A row = pix*8 + plane
  const int plane = lane & 7;
  const int khalf = lane >> 5;
  const int dh = pix >> 1, dw = pix & 1;
  const uint8_t* lbase0 = ldsx + (dh * 40 + dw) * 64 + khalf * 16;

  const int co = g * 32 + (lane & 31);
  const float bs = bias[co];
  const float cm = ldexpf(cti[co], (int)cts[co]);  // i * 2^s == i / 2^-s exact
  const float sm = ldexpf(sti[0], (int)sts[0]);
  const float am = ldexpf(ati[0], (int)ats[0]);
  float pwl[4];                                // this lane's 4 plane weights
  pwl[0] = khalf ? 16.f : 1.f;
  pwl[1] = khalf ? 32.f : 2.f;
  pwl[2] = khalf ? 64.f : 4.f;
  pwl[3] = khalf ? -128.f : 8.f;

  __syncthreads();                             // x strip ready

  for (int q = 0; q < 8; ++q) {
    const int wol = wog * 8 + q;               // 0..15 within block
    const int w = (wq * 16 + wol) * 2;
    const uint8_t* lb = lbase0 + wol * 128;

    // hoist epilogue byte-loads above the MFMA chain (latency hides under it)
    int mgv[4], gtv[4];
#pragma unroll
    for (int px = 0; px < 4; ++px) {
      const size_t moff =
          ((size_t)((b * 128 + h + (px >> 1)) * 128 + w + (px & 1))) * 64 + co;
      mgv[px] = mg[moff];
      gtv[px] = gt[moff];
    }

    i32x16 acc = {};
#pragma unroll
    for (int c = 0; c < 18; ++c) {             // K = 18 chunks of 32
      const int tap = c >> 1;
      const int kh = tap / 3, kw = tap % 3;    // compile-time after unroll
      const uint4 vv =                         // imm-offset ds_read_b128
          *(const uint4*)(lb + kh * 2560 + kw * 64 + (c & 1) * 32);
      i32x4 av;                                // bit-plane extract IS the frag
      av[0] = (int)((vv.x >> plane) & 0x01010101u);
      av[1] = (int)((vv.y >> plane) & 0x01010101u);
      av[2] = (int)((vv.z >> plane) & 0x01010101u);
      av[3] = (int)((vv.w >> plane) & 0x01010101u);
      acc = __builtin_amdgcn_mfma_i32_32x32x32_i8(av, Bf[c], acc, 0, 0, 0);
    }

    // ---- epilogue: reg r -> pixel=r>>2, plane=(r&3)+4*khalf ----
    float psum[4];
#pragma unroll
    for (int px = 0; px < 4; ++px) {
      float s = 0.f;
#pragma unroll
      for (int j = 0; j < 4; ++j) {
        const float y = (float)acc[px * 4 + j];
        const float qq = fminf(fmaxf(rintf(y * 0.5f), -128.f), 127.f);
        s = fmaf(pwl[j], 2.f * qq, s);         // plane_w * 2*clip(rne(y/2))
      }
      psum[px] = s;
    }
#pragma unroll
    for (int px = 0; px < 4; ++px)             // combine plane halves
      psum[px] += __shfl_xor(psum[px], 32);

    float po = -3.0e38f;
#pragma unroll
    for (int px = 0; px < 4; ++px) {
      const float x1 = psum[px] + bs + (float)mgv[px];
      const float x2 = fminf(fmaxf(rintf(x1 * cm), -128.f), 127.f);
      const float x3 = x2 + (float)gtv[px];
      const float x4 = fminf(fmaxf(rintf(x3 * sm), -128.f), 127.f);
      const float x5 = fmaxf(x4, 0.f);
      const float x6 = fminf(fmaxf(rintf(x5 * am), -128.f), 127.f);
      po = fmaxf(po, x6);                      // 2x2 maxpool, in-lane
    }
    if (lane < 32) po_lds[wol * 64 + co] = po; // bank-conflict-free (co spans 32)
  }

  __syncthreads();                             // all 16x64 pooled values ready
  // ---- NCHW store: thread t -> co=t>>2, 4 contiguous wo (one 16B store) ----
  {
    const int tco = tid >> 2, seg = tid & 3;
    float4 v;
    v.x = po_lds[(seg * 4 + 0) * 64 + tco];
    v.y = po_lds[(seg * 4 + 1) * 64 + tco];
    v.z = po_lds[(seg * 4 + 2) * 64 + tco];
    v.w = po_lds[(seg * 4 + 3) * 64 + tco];
    float* dst = outp + (((size_t)(b * 64 + tco)) * 64 + ho) * 64 + wq * 16 + seg * 4;
    *(float4*)dst = v;
  }
}

extern "C" void kernel_launch(void* const* d_in, const int* in_sizes, int n_in,
                              void* d_out, int out_size, void* d_ws, size_t ws_size,
                              hipStream_t stream) {
  const float* cast_in = (const float*)d_in[0];
  const float* merge_in = (const float*)d_in[1];
  const float* gather_in = (const float*)d_in[2];
  const float* conv_w = (const float*)d_in[3];
  const float* conv_b = (const float*)d_in[4];
  const float* cti = (const float*)d_in[5];
  const float* cts = (const float*)d_in[6];
  const float* sti = (const float*)d_in[7];
  const float* sts = (const float*)d_in[8];
  const float* ati = (const float*)d_in[9];
  const float* ats = (const float*)d_in[10];

  uint8_t* ws = (uint8_t*)d_ws;
  uint8_t* xb = ws + XB_OFF;
  int8_t* mg = (int8_t*)(ws + MG_OFF);
  int8_t* gt = (int8_t*)(ws + GT_OFF);
  int8_t* wpk = (int8_t*)(ws + WPK_OFF);

  k_stage<<<1688, 256, 0, stream>>>(cast_in, merge_in, gather_in, conv_w, ws);
  k_main<<<1024, 256, 0, stream>>>(xb, mg, gt, wpk, conv_b, cti, cts, sti, sts,
                                   ati, ats, (float*)d_out);
}

// Round 5
// 41.075 us; speedup vs baseline: 2.3502x; 1.0059x over previous
//
#include <hip/hip_runtime.h>
#include <cstdint>

// ---------------------------------------------------------------------------
// TileTask_62277025792545: bit-serial int8 conv emulation.
//   conv: 8 bit-planes of cast_in (two's complement), each 3x3x64->64 conv,
//   per-plane q = 2*clip(rne(y/2),-128,127), recombine with [1,2,..,64,-128],
//   +bias, +merge, quant(cmult), +gather, quant(0.75), relu, quant(1), pool2x2.
// Implementation: implicit-GEMM MFMA (i8), M=(pixel,plane), N=cout, K=ci*9=576.
// Wave tile: 32 rows = 2x2 pool-quad (4 px) x 8 planes  X  32 cout.
// R5: two independent accumulator chains per wave (quad pairs) to fix the
// MFMA ILP bottleneck diagnosed at ~29% util; launch_bounds (256,3).
// ---------------------------------------------------------------------------

typedef int i32x4  __attribute__((ext_vector_type(4)));
typedef int i32x16 __attribute__((ext_vector_type(16)));

#define XB_OFF   0u
#define XB_BYTES 4326400u                      // 4*130*130*64 u8, padded NHWC
#define MG_OFF   (XB_OFF + XB_BYTES)           // merge int8 NHWC
#define MG_BYTES 4194304u                      // 4*128*128*64
#define GT_OFF   (MG_OFF + MG_BYTES)           // gather int8 NHWC
#define WPK_OFF  (GT_OFF + MG_BYTES)           // packed i8 B-frags
#define WPK_BYTES 36864u                       // 18*2*64*16 i8

// NCHW f32 (ints in [-128,127]) -> NHWC bytes, 3 tensors + weight pack + halo
// zeroing, one launch. which==0 (cast_in) adds the conv halo offset (130x130).
__global__ __launch_bounds__(256) void k_stage(const float* __restrict__ s_cast,
                                               const float* __restrict__ s_mg,
                                               const float* __restrict__ s_gt,
                                               const float* __restrict__ wsrc,
                                               uint8_t* __restrict__ ws) {
  const int blk = blockIdx.x, t = threadIdx.x;
  if (blk >= 1680) {                           // ---- halo top/bottom rows ----
    const int hb = blk - 1680;                 // 8 blocks: 4 b x {0,129}
    const int b = hb >> 1, r = (hb & 1) ? 129 : 0;
    uint8_t* base = ws + XB_OFF + ((size_t)(b * 130 + r) * 130) * 64;
    const uint4 z = {0, 0, 0, 0};
#pragma unroll
    for (int i = 0; i < 3; ++i) {
      const int s = i * 256 + t;
      if (s < 520) *(uint4*)(base + (size_t)s * 16) = z;   // 520*16 = 8320
    }
    return;
  }
  if (blk >= 1536) {                           // ---- weight pack path ----
    const int idx = (blk - 1536) * 256 + t;    // covers exactly 36864
    const int i = idx & 15, l = (idx >> 4) & 63, gg = (idx >> 10) & 1,
              c = idx >> 11;                   // c in [0,18)
    const int k = c * 32 + (l >> 5) * 16 + i;  // k = tap*64 + ci
    const int tap = k >> 6, ci = k & 63;
    const int kh = tap / 3, kw = tap % 3;
    const int cco = gg * 32 + (l & 31);
    const float wv = wsrc[((cco * 64 + ci) * 3 + kh) * 3 + kw];
    ((int8_t*)(ws + WPK_OFF))[idx] = (int8_t)(int)wv;
    return;
  }
  const int which = blk >> 9, rem = blk & 511;
  const float* src = which == 0 ? s_cast : (which == 1 ? s_mg : s_gt);
  uint8_t* dst = which == 0 ? (ws + XB_OFF)
                            : (which == 1 ? (ws + MG_OFF) : (ws + GT_OFF));
  const int b = rem >> 7, h = rem & 127;
  __shared__ uint8_t lds[128 * 68];            // [w][ci], +4 pad for banks
  const float* s0 = src + ((size_t)(b * 64) * 128 + h) * 128;
#pragma unroll
  for (int ci0 = 0; ci0 < 64; ci0 += 2) {
    const int ci = ci0 + (t >> 7), w = t & 127;
    const float v = s0[ci * 16384 + w];        // coalesced over w
    lds[w * 68 + ci] = (uint8_t)((int)v & 0xFF);
  }
  __syncthreads();
  if (which == 0) {
    uint8_t* row = dst + (((size_t)b * 130 + h + 1) * 130) * 64;
#pragma unroll
    for (int j = 0; j < 8; ++j) {              // interior cols 1..128
      const int f = j * 256 + t;
      const int w = f >> 4, ci4 = f & 15;
      const uint32_t val = *(const uint32_t*)&lds[w * 68 + ci4 * 4];
      *(uint32_t*)(row + 64 + (size_t)f * 4) = val;
    }
    if (t < 8) {                               // side halo cols 0 and 129
      const int col = (t < 4) ? 0 : 129, seg = t & 3;
      const uint4 z = {0, 0, 0, 0};
      *(uint4*)(row + (size_t)col * 64 + seg * 16) = z;
    }
  } else {
    uint8_t* d0 = dst + ((size_t)(b * 128 + h) * 128) * 64;
#pragma unroll
    for (int j = 0; j < 8; ++j) {              // 8192B contiguous per (b,h)
      const int f = j * 256 + t;
      const int w = f >> 4, ci4 = f & 15;
      const uint32_t val = *(const uint32_t*)&lds[w * 68 + ci4 * 4];
      *(uint32_t*)(d0 + (size_t)f * 4) = val;
    }
  }
}

__global__ __launch_bounds__(256, 3) void k_main(
    const unsigned char* __restrict__ xb, const signed char* __restrict__ mg,
    const signed char* __restrict__ gt, const int8_t* __restrict__ wpk,
    const float* __restrict__ bias, const float* __restrict__ cti,
    const float* __restrict__ cts, const float* __restrict__ sti,
    const float* __restrict__ sts, const float* __restrict__ ati,
    const float* __restrict__ ats, float* __restrict__ outp) {
  const int tid = threadIdx.x, lane = tid & 63, wvid = tid >> 6;
  const int g = wvid & 1;                      // cout half
  const int wog = wvid >> 1;                   // {0,1}: 8 pooled cols each
  const int blk = blockIdx.x;
  const int wq = blk & 3, ho = (blk >> 2) & 63, b = blk >> 8;
  const int h = ho * 2, w0 = wq * 32;          // block covers cols w0..w0+33

  __shared__ uint4 ldsx4[640];                 // x strip: [4 rows][40 cols][64 ci]
  __shared__ float po_lds[16 * 64];            // pooled out: [wo_local][co]
  uint8_t* ldsx = (uint8_t*)ldsx4;

  // ---- stage x rows h..h+3, padded cols w0..w0+33 into LDS ----
  {
    const unsigned char* xrow = xb + ((size_t)(b * 130 + h) * 130 + w0) * 64;
#pragma unroll
    for (int i = 0; i < 3; ++i) {
      const int s = i * 256 + tid;             // 640 x 16B segments
      if (s < 640) {
        const int row = s / 160, rm = s - row * 160;
        const int col = rm >> 2, ci16 = rm & 3;
        const int gcol = col < 34 ? col : 33;  // pad cols: safe duplicate
        const uint4 v =
            *(const uint4*)(xrow + ((size_t)row * 130 + gcol) * 64 + ci16 * 16);
        *(uint4*)(ldsx + (row * 40 + col) * 64 + ci16 * 16) = v;
      }
    }
  }

  // ---- B fragments in registers (72 VGPR), reused by all 8 quads ----
  i32x4 Bf[18];
#pragma unroll
  for (int c = 0; c < 18; ++c)
    Bf[c] = *(const i32x4*)(wpk + ((size_t)(c * 2 + g) * 64 + lane) * 16);

  const int pix = (lane & 31) >> 3;            // A row = pix*8 + plane
  const int plane = lane & 7;
  const int khalf = lane >> 5;
  const int dh = pix >> 1, dw = pix & 1;
  const uint8_t* lbase0 = ldsx + (dh * 40 + dw) * 64 + khalf * 16;

  const int co = g * 32 + (lane & 31);
  const float bs = bias[co];
  const float cm = ldexpf(cti[co], (int)cts[co]);  // i * 2^s == i / 2^-s exact
  const float sm = ldexpf(sti[0], (int)sts[0]);
  const float am = ldexpf(ati[0], (int)ats[0]);
  float pwl[4];                                // this lane's 4 plane weights
  pwl[0] = khalf ? 16.f : 1.f;
  pwl[1] = khalf ? 32.f : 2.f;
  pwl[2] = khalf ? 64.f : 4.f;
  pwl[3] = khalf ? -128.f : 8.f;

  __syncthreads();                             // x strip ready

  for (int qp = 0; qp < 4; ++qp) {             // quad PAIRS: 2 indep acc chains
    const int wolA = wog * 8 + qp * 2;         // 0..15 within block
    const int wolB = wolA + 1;
    const int wA = (wq * 16 + wolA) * 2, wB = wA + 2;
    const uint8_t* lbA = lbase0 + wolA * 128;
    const uint8_t* lbB = lbA + 128;

    // hoist both quads' epilogue byte-loads above the MFMA chains
    int mgvA[4], gtvA[4], mgvB[4], gtvB[4];
#pragma unroll
    for (int px = 0; px < 4; ++px) {
      const size_t rbase =
          ((size_t)((b * 128 + h + (px >> 1)) * 128 + (px & 1))) * 64 + co;
      mgvA[px] = mg[rbase + (size_t)wA * 64];
      gtvA[px] = gt[rbase + (size_t)wA * 64];
      mgvB[px] = mg[rbase + (size_t)wB * 64];
      gtvB[px] = gt[rbase + (size_t)wB * 64];
    }

    i32x16 accA = {}, accB = {};
#pragma unroll
    for (int c = 0; c < 18; ++c) {             // K = 18 chunks of 32
      const int tap = c >> 1;
      const int kh = tap / 3, kw = tap % 3;    // compile-time after unroll
      const int off = kh * 2560 + kw * 64 + (c & 1) * 32;
      const uint4 vvA = *(const uint4*)(lbA + off);   // imm-offset ds_read_b128
      const uint4 vvB = *(const uint4*)(lbB + off);
      i32x4 avA, avB;                          // bit-plane extract IS the frag
      avA[0] = (int)((vvA.x >> plane) & 0x01010101u);
      avA[1] = (int)((vvA.y >> plane) & 0x01010101u);
      avA[2] = (int)((vvA.z >> plane) & 0x01010101u);
      avA[3] = (int)((vvA.w >> plane) & 0x01010101u);
      avB[0] = (int)((vvB.x >> plane) & 0x01010101u);
      avB[1] = (int)((vvB.y >> plane) & 0x01010101u);
      avB[2] = (int)((vvB.z >> plane) & 0x01010101u);
      avB[3] = (int)((vvB.w >> plane) & 0x01010101u);
      accA = __builtin_amdgcn_mfma_i32_32x32x32_i8(avA, Bf[c], accA, 0, 0, 0);
      accB = __builtin_amdgcn_mfma_i32_32x32x32_i8(avB, Bf[c], accB, 0, 0, 0);
    }

    // ---- epilogue x2: reg r -> pixel=r>>2, plane=(r&3)+4*khalf ----
#pragma unroll
    for (int s2 = 0; s2 < 2; ++s2) {
      const i32x16& acc = s2 ? accB : accA;
      const int* mgv = s2 ? mgvB : mgvA;
      const int* gtv = s2 ? gtvB : gtvA;
      const int wol = s2 ? wolB : wolA;
      float psum[4];
#pragma unroll
      for (int px = 0; px < 4; ++px) {
        float s = 0.f;
#pragma unroll
        for (int j = 0; j < 4; ++j) {
          const float y = (float)acc[px * 4 + j];
          const float qq = fminf(fmaxf(rintf(y * 0.5f), -128.f), 127.f);
          s = fmaf(pwl[j], 2.f * qq, s);       // plane_w * 2*clip(rne(y/2))
        }
        psum[px] = s;
      }
#pragma unroll
      for (int px = 0; px < 4; ++px)           // combine plane halves
        psum[px] += __shfl_xor(psum[px], 32);

      float po = -3.0e38f;
#pragma unroll
      for (int px = 0; px < 4; ++px) {
        const float x1 = psum[px] + bs + (float)mgv[px];
        const float x2 = fminf(fmaxf(rintf(x1 * cm), -128.f), 127.f);
        const float x3 = x2 + (float)gtv[px];
        const float x4 = fminf(fmaxf(rintf(x3 * sm), -128.f), 127.f);
        const float x5 = fmaxf(x4, 0.f);
        const float x6 = fminf(fmaxf(rintf(x5 * am), -128.f), 127.f);
        po = fmaxf(po, x6);                    // 2x2 maxpool, in-lane
      }
      if (lane < 32) po_lds[wol * 64 + co] = po;  // conflict-free (co spans 32)
    }
  }

  __syncthreads();                             // all 16x64 pooled values ready
  // ---- NCHW store: thread t -> co=t>>2, 4 contiguous wo (one 16B store) ----
  {
    const int tco = tid >> 2, seg = tid & 3;
    float4 v;
    v.x = po_lds[(seg * 4 + 0) * 64 + tco];
    v.y = po_lds[(seg * 4 + 1) * 64 + tco];
    v.z = po_lds[(seg * 4 + 2) * 64 + tco];
    v.w = po_lds[(seg * 4 + 3) * 64 + tco];
    float* dst = outp + (((size_t)(b * 64 + tco)) * 64 + ho) * 64 + wq * 16 + seg * 4;
    *(float4*)dst = v;
  }
}

extern "C" void kernel_launch(void* const* d_in, const int* in_sizes, int n_in,
                              void* d_out, int out_size, void* d_ws, size_t ws_size,
                              hipStream_t stream) {
  const float* cast_in = (const float*)d_in[0];
  const float* merge_in = (const float*)d_in[1];
  const float* gather_in = (const float*)d_in[2];
  const float* conv_w = (const float*)d_in[3];
  const float* conv_b = (const float*)d_in[4];
  const float* cti = (const float*)d_in[5];
  const float* cts = (const float*)d_in[6];
  const float* sti = (const float*)d_in[7];
  const float* sts = (const float*)d_in[8];
  const float* ati = (const float*)d_in[9];
  const float* ats = (const float*)d_in[10];

  uint8_t* ws = (uint8_t*)d_ws;
  uint8_t* xb = ws + XB_OFF;
  int8_t* mg = (int8_t*)(ws + MG_OFF);
  int8_t* gt = (int8_t*)(ws + GT_OFF);
  int8_t* wpk = (int8_t*)(ws + WPK_OFF);

  k_stage<<<1688, 256, 0, stream>>>(cast_in, merge_in, gather_in, conv_w, ws);
  k_main<<<1024, 256, 0, stream>>>(xb, mg, gt, wpk, conv_b, cti, cts, sti, sts,
                                   ati, ats, (float*)d_out);
}

// Round 6
// 40.506 us; speedup vs baseline: 2.3832x; 1.0141x over previous
//
#include <hip/hip_runtime.h>
#include <cstdint>

// ---------------------------------------------------------------------------
// TileTask_62277025792545: bit-serial int8 conv emulation.
//   conv: 8 bit-planes of cast_in (two's complement), each 3x3x64->64 conv,
//   per-plane q = 2*clip(rne(y/2),-128,127), recombine with [1,2,..,64,-128],
//   +bias, +merge, quant(cmult), +gather, quant(0.75), relu, quant(1), pool2x2.
// Implementation: implicit-GEMM MFMA (i8), M=(pixel,plane), N=cout, K=ci*9=576.
// Wave tile: 32 rows = 2x2 pool-quad (4 px) x 8 planes  X  64 cout (both g).
// R6: one ds_read_b128 + one bit-extract now feeds TWO MFMAs (both cout
// halves) -> LDS pipe no longer oversubscribed (was 1.33x); explicit 3-deep
// chunk pipeline hides LDS latency; launch_bounds (256,2) for ~230 VGPR.
// ---------------------------------------------------------------------------

typedef int i32x4  __attribute__((ext_vector_type(4)));
typedef int i32x16 __attribute__((ext_vector_type(16)));

#define XB_OFF   0u
#define XB_BYTES 4326400u                      // 4*130*130*64 u8, padded NHWC
#define MG_OFF   (XB_OFF + XB_BYTES)           // merge int8 NHWC
#define MG_BYTES 4194304u                      // 4*128*128*64
#define GT_OFF   (MG_OFF + MG_BYTES)           // gather int8 NHWC
#define WPK_OFF  (GT_OFF + MG_BYTES)           // packed i8 B-frags
#define WPK_BYTES 36864u                       // 18*2*64*16 i8

// NCHW f32 (ints in [-128,127]) -> NHWC bytes, 3 tensors + weight pack + halo
// zeroing, one launch. which==0 (cast_in) adds the conv halo offset (130x130).
// This kernel is HBM-floor-bound (63MB @ ~6 TB/s ~= 10.5us) — do not touch.
__global__ __launch_bounds__(256) void k_stage(const float* __restrict__ s_cast,
                                               const float* __restrict__ s_mg,
                                               const float* __restrict__ s_gt,
                                               const float* __restrict__ wsrc,
                                               uint8_t* __restrict__ ws) {
  const int blk = blockIdx.x, t = threadIdx.x;
  if (blk >= 1680) {                           // ---- halo top/bottom rows ----
    const int hb = blk - 1680;                 // 8 blocks: 4 b x {0,129}
    const int b = hb >> 1, r = (hb & 1) ? 129 : 0;
    uint8_t* base = ws + XB_OFF + ((size_t)(b * 130 + r) * 130) * 64;
    const uint4 z = {0, 0, 0, 0};
#pragma unroll
    for (int i = 0; i < 3; ++i) {
      const int s = i * 256 + t;
      if (s < 520) *(uint4*)(base + (size_t)s * 16) = z;   // 520*16 = 8320
    }
    return;
  }
  if (blk >= 1536) {                           // ---- weight pack path ----
    const int idx = (blk - 1536) * 256 + t;    // covers exactly 36864
    const int i = idx & 15, l = (idx >> 4) & 63, gg = (idx >> 10) & 1,
              c = idx >> 11;                   // c in [0,18)
    const int k = c * 32 + (l >> 5) * 16 + i;  // k = tap*64 + ci
    const int tap = k >> 6, ci = k & 63;
    const int kh = tap / 3, kw = tap % 3;
    const int cco = gg * 32 + (l & 31);
    const float wv = wsrc[((cco * 64 + ci) * 3 + kh) * 3 + kw];
    ((int8_t*)(ws + WPK_OFF))[idx] = (int8_t)(int)wv;
    return;
  }
  const int which = blk >> 9, rem = blk & 511;
  const float* src = which == 0 ? s_cast : (which == 1 ? s_mg : s_gt);
  uint8_t* dst = which == 0 ? (ws + XB_OFF)
                            : (which == 1 ? (ws + MG_OFF) : (ws + GT_OFF));
  const int b = rem >> 7, h = rem & 127;
  __shared__ uint8_t lds[128 * 68];            // [w][ci], +4 pad for banks
  const float* s0 = src + ((size_t)(b * 64) * 128 + h) * 128;
#pragma unroll
  for (int ci0 = 0; ci0 < 64; ci0 += 2) {
    const int ci = ci0 + (t >> 7), w = t & 127;
    const float v = s0[ci * 16384 + w];        // coalesced over w
    lds[w * 68 + ci] = (uint8_t)((int)v & 0xFF);
  }
  __syncthreads();
  if (which == 0) {
    uint8_t* row = dst + (((size_t)b * 130 + h + 1) * 130) * 64;
#pragma unroll
    for (int j = 0; j < 8; ++j) {              // interior cols 1..128
      const int f = j * 256 + t;
      const int w = f >> 4, ci4 = f & 15;
      const uint32_t val = *(const uint32_t*)&lds[w * 68 + ci4 * 4];
      *(uint32_t*)(row + 64 + (size_t)f * 4) = val;
    }
    if (t < 8) {                               // side halo cols 0 and 129
      const int col = (t < 4) ? 0 : 129, seg = t & 3;
      const uint4 z = {0, 0, 0, 0};
      *(uint4*)(row + (size_t)col * 64 + seg * 16) = z;
    }
  } else {
    uint8_t* d0 = dst + ((size_t)(b * 128 + h) * 128) * 64;
#pragma unroll
    for (int j = 0; j < 8; ++j) {              // 8192B contiguous per (b,h)
      const int f = j * 256 + t;
      const int w = f >> 4, ci4 = f & 15;
      const uint32_t val = *(const uint32_t*)&lds[w * 68 + ci4 * 4];
      *(uint32_t*)(d0 + (size_t)f * 4) = val;
    }
  }
}

__global__ __launch_bounds__(256, 2) void k_main(
    const unsigned char* __restrict__ xb, const signed char* __restrict__ mg,
    const signed char* __restrict__ gt, const int8_t* __restrict__ wpk,
    const float* __restrict__ bias, const float* __restrict__ cti,
    const float* __restrict__ cts, const float* __restrict__ sti,
    const float* __restrict__ sts, const float* __restrict__ ati,
    const float* __restrict__ ats, float* __restrict__ outp) {
  const int tid = threadIdx.x, lane = tid & 63, wv = tid >> 6;
  const int blk = blockIdx.x;
  const int wq = blk & 3, ho = (blk >> 2) & 63, b = blk >> 8;
  const int h = ho * 2, w0 = wq * 32;          // block covers cols w0..w0+33

  __shared__ uint4 ldsx4[640];                 // x strip: [4 rows][40 cols][64 ci]
  __shared__ float po_lds[16 * 64];            // pooled out: [wo_local][co]
  uint8_t* ldsx = (uint8_t*)ldsx4;

  // ---- stage x rows h..h+3, padded cols w0..w0+33 into LDS ----
  {
    const unsigned char* xrow = xb + ((size_t)(b * 130 + h) * 130 + w0) * 64;
#pragma unroll
    for (int i = 0; i < 3; ++i) {
      const int s = i * 256 + tid;             // 640 x 16B segments
      if (s < 640) {
        const int row = s / 160, rm = s - row * 160;
        const int col = rm >> 2, ci16 = rm & 3;
        const int gcol = col < 34 ? col : 33;  // pad cols: safe duplicate
        const uint4 v =
            *(const uint4*)(xrow + ((size_t)row * 130 + gcol) * 64 + ci16 * 16);
        *(uint4*)(ldsx + (row * 40 + col) * 64 + ci16 * 16) = v;
      }
    }
  }

  // ---- B fragments for BOTH cout halves in regs (144 VGPR) ----
  i32x4 Bf[36];                                // [c][g]
#pragma unroll
  for (int cg = 0; cg < 36; ++cg)
    Bf[cg] = *(const i32x4*)(wpk + ((size_t)cg * 64 + lane) * 16);

  const int pix = (lane & 31) >> 3;            // A row = pix*8 + plane
  const int plane = lane & 7;
  const int khalf = lane >> 5;
  const int dh = pix >> 1, dw = pix & 1;
  const uint8_t* lbase0 = ldsx + (dh * 40 + dw) * 64 + khalf * 16;

  const int col = lane & 31;                   // cout within half
  const float bs0 = bias[col], bs1 = bias[col + 32];
  const float cm0 = ldexpf(cti[col], (int)cts[col]);        // exact: i * 2^s
  const float cm1 = ldexpf(cti[col + 32], (int)cts[col + 32]);
  const float sm = ldexpf(sti[0], (int)sts[0]);
  const float am = ldexpf(ati[0], (int)ats[0]);
  float pwl[4];                                // this lane's 4 plane weights
  pwl[0] = khalf ? 16.f : 1.f;
  pwl[1] = khalf ? 32.f : 2.f;
  pwl[2] = khalf ? 64.f : 4.f;
  pwl[3] = khalf ? -128.f : 8.f;

  __syncthreads();                             // x strip ready

  for (int q = 0; q < 4; ++q) {                // each wave: 4 quads x both g
    const int wol = wv * 4 + q;                // 0..15 within block
    const int w = (wq * 16 + wol) * 2;
    const uint8_t* lb = lbase0 + wol * 128;

    // hoist epilogue byte-loads above the MFMA chain (latency hides under it)
    int mgv[8], gtv[8];                        // [g*4+px]
#pragma unroll
    for (int px = 0; px < 4; ++px) {
      const size_t moff =
          ((size_t)((b * 128 + h + (px >> 1)) * 128 + w + (px & 1))) * 64 + col;
      mgv[px] = mg[moff];
      gtv[px] = gt[moff];
      mgv[4 + px] = mg[moff + 32];
      gtv[4 + px] = gt[moff + 32];
    }

    // ---- 3-deep pipelined K loop: 18 chunks of 32, 2 MFMAs per chunk ----
#define XOFF(c) ((((c) >> 1) / 3) * 2560 + (((c) >> 1) % 3) * 64 + ((c)&1) * 32)
    uint4 p0 = *(const uint4*)(lb + XOFF(0));
    uint4 p1 = *(const uint4*)(lb + XOFF(1));
    uint4 p2 = *(const uint4*)(lb + XOFF(2));
    i32x16 a0 = {}, a1 = {};
#pragma unroll
    for (int c = 0; c < 18; ++c) {             // fully unrolled: static slots
      uint4 cur;
      if (c % 3 == 0) cur = p0;
      else if (c % 3 == 1) cur = p1;
      else cur = p2;
      if (c + 3 < 18) {                        // prefetch chunk c+3
        const uint4 nv = *(const uint4*)(lb + XOFF(c + 3));
        if (c % 3 == 0) p0 = nv;
        else if (c % 3 == 1) p1 = nv;
        else p2 = nv;
      }
      i32x4 av;                                // bit-plane extract IS the frag
      av[0] = (int)((cur.x >> plane) & 0x01010101u);
      av[1] = (int)((cur.y >> plane) & 0x01010101u);
      av[2] = (int)((cur.z >> plane) & 0x01010101u);
      av[3] = (int)((cur.w >> plane) & 0x01010101u);
      a0 = __builtin_amdgcn_mfma_i32_32x32x32_i8(av, Bf[c * 2 + 0], a0, 0, 0, 0);
      a1 = __builtin_amdgcn_mfma_i32_32x32x32_i8(av, Bf[c * 2 + 1], a1, 0, 0, 0);
    }
#undef XOFF

    // ---- epilogue x2 g: reg r -> pixel=r>>2, plane=(r&3)+4*khalf ----
#pragma unroll
    for (int gg = 0; gg < 2; ++gg) {
      const i32x16& acc = gg ? a1 : a0;
      const float bs = gg ? bs1 : bs0;
      const float cm = gg ? cm1 : cm0;
      float psum[4];
#pragma unroll
      for (int px = 0; px < 4; ++px) {
        float s = 0.f;
#pragma unroll
        for (int j = 0; j < 4; ++j) {
          const float y = (float)acc[px * 4 + j];
          const float qq = fminf(fmaxf(rintf(y * 0.5f), -128.f), 127.f);
          s = fmaf(pwl[j], 2.f * qq, s);       // plane_w * 2*clip(rne(y/2))
        }
        psum[px] = s;
      }
#pragma unroll
      for (int px = 0; px < 4; ++px)           // combine plane halves
        psum[px] += __shfl_xor(psum[px], 32);

      float po = -3.0e38f;
#pragma unroll
      for (int px = 0; px < 4; ++px) {
        const float x1 = psum[px] + bs + (float)mgv[gg * 4 + px];
        const float x2 = fminf(fmaxf(rintf(x1 * cm), -128.f), 127.f);
        const float x3 = x2 + (float)gtv[gg * 4 + px];
        const float x4 = fminf(fmaxf(rintf(x3 * sm), -128.f), 127.f);
        const float x5 = fmaxf(x4, 0.f);
        const float x6 = fminf(fmaxf(rintf(x5 * am), -128.f), 127.f);
        po = fmaxf(po, x6);                    // 2x2 maxpool, in-lane
      }
      if (lane < 32)
        po_lds[wol * 64 + gg * 32 + col] = po; // conflict-free (stride 1)
    }
  }

  __syncthreads();                             // all 16x64 pooled values ready
  // ---- NCHW store: thread t -> co=t>>2, 4 contiguous wo (one 16B store) ----
  {
    const int tco = tid >> 2, seg = tid & 3;
    float4 v;
    v.x = po_lds[(seg * 4 + 0) * 64 + tco];
    v.y = po_lds[(seg * 4 + 1) * 64 + tco];
    v.z = po_lds[(seg * 4 + 2) * 64 + tco];
    v.w = po_lds[(seg * 4 + 3) * 64 + tco];
    float* dst = outp + (((size_t)(b * 64 + tco)) * 64 + ho) * 64 + wq * 16 + seg * 4;
    *(float4*)dst = v;
  }
}

extern "C" void kernel_launch(void* const* d_in, const int* in_sizes, int n_in,
                              void* d_out, int out_size, void* d_ws, size_t ws_size,
                              hipStream_t stream) {
  const float* cast_in = (const float*)d_in[0];
  const float* merge_in = (const float*)d_in[1];
  const float* gather_in = (const float*)d_in[2];
  const float* conv_w = (const float*)d_in[3];
  const float* conv_b = (const float*)d_in[4];
  const float* cti = (const float*)d_in[5];
  const float* cts = (const float*)d_in[6];
  const float* sti = (const float*)d_in[7];
  const float* sts = (const float*)d_in[8];
  const float* ati = (const float*)d_in[9];
  const float* ats = (const float*)d_in[10];

  uint8_t* ws = (uint8_t*)d_ws;
  uint8_t* xb = ws + XB_OFF;
  int8_t* mg = (int8_t*)(ws + MG_OFF);
  int8_t* gt = (int8_t*)(ws + GT_OFF);
  int8_t* wpk = (int8_t*)(ws + WPK_OFF);

  k_stage<<<1688, 256, 0, stream>>>(cast_in, merge_in, gather_in, conv_w, ws);
  k_main<<<1024, 256, 0, stream>>>(xb, mg, gt, wpk, conv_b, cti, cts, sti, sts,
                                   ati, ats, (float*)d_out);
}

// Round 7
// 35.404 us; speedup vs baseline: 2.7267x; 1.1441x over previous
//
#include <hip/hip_runtime.h>
#include <cstdint>

// ---------------------------------------------------------------------------
// TileTask_62277025792545: bit-serial int8 conv emulation.
//   conv: 8 bit-planes of cast_in (two's complement), each 3x3x64->64 conv,
//   per-plane q = 2*clip(rne(y/2),-128,127), recombine with [1,2,..,64,-128],
//   +bias, +merge, quant(cmult), +gather, quant(0.75), relu, quant(1), pool2x2.
// Implementation: implicit-GEMM MFMA (i8), M=(pixel,plane), N=cout, K=ci*9=576.
// Wave tile: 32 rows = 2x2 pool-quad (4 px) x 8 planes  X  64 cout (both g).
// R7: mg/gt staging pass REMOVED — k_main reads them as f32 through a
// 65-padded LDS transpose tile (coalesced global, conflict-free LDS both
// directions). Kills the per-quad scalar byte-loads and ~29MB of HBM traffic.
// k_stage is now cast-only + weight-pack + halo (~21MB, ~4us).
// ---------------------------------------------------------------------------

typedef int i32x4  __attribute__((ext_vector_type(4)));
typedef int i32x16 __attribute__((ext_vector_type(16)));

#define XB_OFF   0u
#define XB_BYTES 4326400u                      // 4*130*130*64 u8, padded NHWC
#define WPK_OFF  XB_BYTES                      // packed i8 B-frags
#define WPK_BYTES 36864u                       // 18*2*64*16 i8

// cast_in NCHW f32 -> NHWC bytes with halo (130x130), + weight pack + halo
// row zeroing. Blocks 0..511 cast, 512..655 pack, 656..663 halo rows.
__global__ __launch_bounds__(256) void k_stage(const float* __restrict__ s_cast,
                                               const float* __restrict__ wsrc,
                                               uint8_t* __restrict__ ws) {
  const int blk = blockIdx.x, t = threadIdx.x;
  if (blk >= 656) {                            // ---- halo top/bottom rows ----
    const int hb = blk - 656;                  // 8 blocks: 4 b x {0,129}
    const int b = hb >> 1, r = (hb & 1) ? 129 : 0;
    uint8_t* base = ws + XB_OFF + ((size_t)(b * 130 + r) * 130) * 64;
    const uint4 z = {0, 0, 0, 0};
#pragma unroll
    for (int i = 0; i < 3; ++i) {
      const int s = i * 256 + t;
      if (s < 520) *(uint4*)(base + (size_t)s * 16) = z;   // 520*16 = 8320
    }
    return;
  }
  if (blk >= 512) {                            // ---- weight pack path ----
    const int idx = (blk - 512) * 256 + t;     // covers exactly 36864
    const int i = idx & 15, l = (idx >> 4) & 63, gg = (idx >> 10) & 1,
              c = idx >> 11;                   // c in [0,18)
    const int k = c * 32 + (l >> 5) * 16 + i;  // k = tap*64 + ci
    const int tap = k >> 6, ci = k & 63;
    const int kh = tap / 3, kw = tap % 3;
    const int cco = gg * 32 + (l & 31);
    const float wv = wsrc[((cco * 64 + ci) * 3 + kh) * 3 + kw];
    ((int8_t*)(ws + WPK_OFF))[idx] = (int8_t)(int)wv;
    return;
  }
  const int b = blk >> 7, h = blk & 127;       // ---- cast path ----
  __shared__ uint8_t lds[128 * 68];            // [w][ci], +4 pad for banks
  const float* s0 = s_cast + ((size_t)(b * 64) * 128 + h) * 128;
#pragma unroll
  for (int ci0 = 0; ci0 < 64; ci0 += 2) {
    const int ci = ci0 + (t >> 7), w = t & 127;
    const float v = s0[ci * 16384 + w];        // coalesced over w
    lds[w * 68 + ci] = (uint8_t)((int)v & 0xFF);
  }
  __syncthreads();
  uint8_t* row = ws + XB_OFF + (((size_t)b * 130 + h + 1) * 130) * 64;
#pragma unroll
  for (int j = 0; j < 8; ++j) {                // interior cols 1..128
    const int f = j * 256 + t;
    const int w = f >> 4, ci4 = f & 15;
    const uint32_t val = *(const uint32_t*)&lds[w * 68 + ci4 * 4];
    *(uint32_t*)(row + 64 + (size_t)f * 4) = val;
  }
  if (t < 8) {                                 // side halo cols 0 and 129
    const int col = (t < 4) ? 0 : 129, seg = t & 3;
    const uint4 z = {0, 0, 0, 0};
    *(uint4*)(row + (size_t)col * 64 + seg * 16) = z;
  }
}

__global__ __launch_bounds__(256, 2) void k_main(
    const unsigned char* __restrict__ xb, const float* __restrict__ mgf,
    const float* __restrict__ gtf, const int8_t* __restrict__ wpk,
    const float* __restrict__ bias, const float* __restrict__ cti,
    const float* __restrict__ cts, const float* __restrict__ sti,
    const float* __restrict__ sts, const float* __restrict__ ati,
    const float* __restrict__ ats, float* __restrict__ outp) {
  const int tid = threadIdx.x, lane = tid & 63, wv = tid >> 6;
  const int blk = blockIdx.x;
  const int wq = blk & 3, ho = (blk >> 2) & 63, b = blk >> 8;
  const int h = ho * 2, w0 = wq * 32;          // block: 32 actual w cols

  __shared__ uint4 ldsx4[640];                 // x strip: [4 rows][40 cols][64 ci]
  __shared__ float mgt[2][2][32][65];          // [mg/gt][hh][w][co], 65-pad
  __shared__ float po_lds[16 * 64];            // pooled out: [wo_local][co]
  uint8_t* ldsx = (uint8_t*)ldsx4;

  // ---- stage x rows h..h+3, padded cols w0..w0+33 into LDS ----
  {
    const unsigned char* xrow = xb + ((size_t)(b * 130 + h) * 130 + w0) * 64;
#pragma unroll
    for (int i = 0; i < 3; ++i) {
      const int s = i * 256 + tid;             // 640 x 16B segments
      if (s < 640) {
        const int row = s / 160, rm = s - row * 160;
        const int col = rm >> 2, ci16 = rm & 3;
        const int gcol = col < 34 ? col : 33;  // pad cols: safe duplicate
        const uint4 v =
            *(const uint4*)(xrow + ((size_t)row * 130 + gcol) * 64 + ci16 * 16);
        *(uint4*)(ldsx + (row * 40 + col) * 64 + ci16 * 16) = v;
      }
    }
  }

  // ---- stage merge/gather f32 (b, co 0..63, rows h..h+1, cols w0..w0+31) ----
  // slot -> co=slot>>4 (slow: 4 co per wave -> 128B-coalesced global reads);
  // LDS bank = (w+co)%32 over (co,seg) = all 32, 2 lanes (hh) each -> free.
#pragma unroll
  for (int which = 0; which < 2; ++which) {
    const float* sp = which ? gtf : mgf;
#pragma unroll
    for (int i = 0; i < 4; ++i) {
      const int slot = i * 256 + tid;          // 0..1023
      const int co = slot >> 4, r = slot & 15, hh = r & 1, seg = r >> 1;
      const float4 v = *(const float4*)(
          sp + ((size_t)((b * 64 + co) * 128 + h + hh)) * 128 + w0 + seg * 4);
      float* dst = &mgt[which][hh][seg * 4][co];
      dst[0] = v.x; dst[65] = v.y; dst[130] = v.z; dst[195] = v.w;
    }
  }

  // ---- B fragments for BOTH cout halves in regs (144 VGPR) ----
  i32x4 Bf[36];                                // [c][g]
#pragma unroll
  for (int cg = 0; cg < 36; ++cg)
    Bf[cg] = *(const i32x4*)(wpk + ((size_t)cg * 64 + lane) * 16);

  const int pix = (lane & 31) >> 3;            // A row = pix*8 + plane
  const int plane = lane & 7;
  const int khalf = lane >> 5;
  const int dh = pix >> 1, dw = pix & 1;
  const uint8_t* lbase0 = ldsx + (dh * 40 + dw) * 64 + khalf * 16;

  const int col = lane & 31;                   // cout within half
  const float bs0 = bias[col], bs1 = bias[col + 32];
  const float cm0 = ldexpf(cti[col], (int)cts[col]);        // exact: i * 2^s
  const float cm1 = ldexpf(cti[col + 32], (int)cts[col + 32]);
  const float sm = ldexpf(sti[0], (int)sts[0]);
  const float am = ldexpf(ati[0], (int)ats[0]);
  float pwl[4];                                // this lane's 4 plane weights
  pwl[0] = khalf ? 16.f : 1.f;
  pwl[1] = khalf ? 32.f : 2.f;
  pwl[2] = khalf ? 64.f : 4.f;
  pwl[3] = khalf ? -128.f : 8.f;

  __syncthreads();                             // x + mg/gt tiles ready

  for (int q = 0; q < 4; ++q) {                // each wave: 4 quads x both g
    const int wol = wv * 4 + q;                // 0..15 within block
    const uint8_t* lb = lbase0 + wol * 128;

    // ---- 3-deep pipelined K loop: 18 chunks of 32, 2 MFMAs per chunk ----
#define XOFF(c) ((((c) >> 1) / 3) * 2560 + (((c) >> 1) % 3) * 64 + ((c)&1) * 32)
    uint4 p0 = *(const uint4*)(lb + XOFF(0));
    uint4 p1 = *(const uint4*)(lb + XOFF(1));
    uint4 p2 = *(const uint4*)(lb + XOFF(2));
    i32x16 a0 = {}, a1 = {};
#pragma unroll
    for (int c = 0; c < 18; ++c) {             // fully unrolled: static slots
      uint4 cur;
      if (c % 3 == 0) cur = p0;
      else if (c % 3 == 1) cur = p1;
      else cur = p2;
      if (c + 3 < 18) {                        // prefetch chunk c+3
        const uint4 nv = *(const uint4*)(lb + XOFF(c + 3));
        if (c % 3 == 0) p0 = nv;
        else if (c % 3 == 1) p1 = nv;
        else p2 = nv;
      }
      i32x4 av;                                // bit-plane extract IS the frag
      av[0] = (int)((cur.x >> plane) & 0x01010101u);
      av[1] = (int)((cur.y >> plane) & 0x01010101u);
      av[2] = (int)((cur.z >> plane) & 0x01010101u);
      av[3] = (int)((cur.w >> plane) & 0x01010101u);
      a0 = __builtin_amdgcn_mfma_i32_32x32x32_i8(av, Bf[c * 2 + 0], a0, 0, 0, 0);
      a1 = __builtin_amdgcn_mfma_i32_32x32x32_i8(av, Bf[c * 2 + 1], a1, 0, 0, 0);
    }
#undef XOFF

    // ---- epilogue x2 g: reg r -> pixel=r>>2, plane=(r&3)+4*khalf ----
#pragma unroll
    for (int gg = 0; gg < 2; ++gg) {
      const i32x16& acc = gg ? a1 : a0;
      const float bs = gg ? bs1 : bs0;
      const float cm = gg ? cm1 : cm0;
      const int cc = gg * 32 + col;
      float psum[4];
#pragma unroll
      for (int px = 0; px < 4; ++px) {
        float s = 0.f;
#pragma unroll
        for (int j = 0; j < 4; ++j) {
          const float y = (float)acc[px * 4 + j];
          const float qq = fminf(fmaxf(rintf(y * 0.5f), -128.f), 127.f);
          s = fmaf(pwl[j], 2.f * qq, s);       // plane_w * 2*clip(rne(y/2))
        }
        psum[px] = s;
      }
#pragma unroll
      for (int px = 0; px < 4; ++px)           // combine plane halves
        psum[px] += __shfl_xor(psum[px], 32);

      float po = -3.0e38f;
#pragma unroll
      for (int px = 0; px < 4; ++px) {
        const int ww = wol * 2 + (px & 1);
        const float x1 = psum[px] + bs + mgt[0][px >> 1][ww][cc];
        const float x2 = fminf(fmaxf(rintf(x1 * cm), -128.f), 127.f);
        const float x3 = x2 + mgt[1][px >> 1][ww][cc];
        const float x4 = fminf(fmaxf(rintf(x3 * sm), -128.f), 127.f);
        const float x5 = fmaxf(x4, 0.f);
        const float x6 = fminf(fmaxf(rintf(x5 * am), -128.f), 127.f);
        po = fmaxf(po, x6);                    // 2x2 maxpool, in-lane
      }
      if (lane < 32)
        po_lds[wol * 64 + gg * 32 + col] = po; // conflict-free (stride 1)
    }
  }

  __syncthreads();                             // all 16x64 pooled values ready
  // ---- NCHW store: thread t -> co=t>>2, 4 contiguous wo (one 16B store) ----
  {
    const int tco = tid >> 2, seg = tid & 3;
    float4 v;
    v.x = po_lds[(seg * 4 + 0) * 64 + tco];
    v.y = po_lds[(seg * 4 + 1) * 64 + tco];
    v.z = po_lds[(seg * 4 + 2) * 64 + tco];
    v.w = po_lds[(seg * 4 + 3) * 64 + tco];
    float* dst = outp + (((size_t)(b * 64 + tco)) * 64 + ho) * 64 + wq * 16 + seg * 4;
    *(float4*)dst = v;
  }
}

extern "C" void kernel_launch(void* const* d_in, const int* in_sizes, int n_in,
                              void* d_out, int out_size, void* d_ws, size_t ws_size,
                              hipStream_t stream) {
  const float* cast_in = (const float*)d_in[0];
  const float* merge_in = (const float*)d_in[1];
  const float* gather_in = (const float*)d_in[2];
  const float* conv_w = (const float*)d_in[3];
  const float* conv_b = (const float*)d_in[4];
  const float* cti = (const float*)d_in[5];
  const float* cts = (const float*)d_in[6];
  const float* sti = (const float*)d_in[7];
  const float* sts = (const float*)d_in[8];
  const float* ati = (const float*)d_in[9];
  const float* ats = (const float*)d_in[10];

  uint8_t* ws = (uint8_t*)d_ws;
  uint8_t* xb = ws + XB_OFF;
  int8_t* wpk = (int8_t*)(ws + WPK_OFF);

  k_stage<<<664, 256, 0, stream>>>(cast_in, conv_w, ws);
  k_main<<<1024, 256, 0, stream>>>(xb, merge_in, gather_in, wpk, conv_b, cti,
                                   cts, sti, sts, ati, ats, (float*)d_out);
}